// Round 2
// baseline (950.838 us; speedup 1.0000x reference)
//
#include <hip/hip_runtime.h>
#include <cstdint>

typedef unsigned short u16;
typedef __attribute__((ext_vector_type(8))) __bf16 bf16x8;
typedef __attribute__((ext_vector_type(4))) float f32x4;

#define N_DIM 4096

__device__ __forceinline__ u16 f2bf(float f) {
    union { float f; unsigned u; } c; c.f = f;
    unsigned u = c.u;
    u += 0x7FFFu + ((u >> 16) & 1u);   // round-nearest-even
    return (u16)(u >> 16);
}

__device__ __forceinline__ void gl_lds16(const u16* g, u16* l) {
    __builtin_amdgcn_global_load_lds(
        (const __attribute__((address_space(1))) void*)g,
        (__attribute__((address_space(3))) void*)l, 16, 0, 0);
}

// ---------------------------------------------------------------------------
// Fused band-build + banded combine + transpose:
// P[din, n] = sum_off M[n, n+off] * v[n+off, din], bf16 row-major [D_IN, N].
// M[n,n+off] = s[spdiags idx]*sigmoid(gate) (+ s_pre[n] on diag).
// ---------------------------------------------------------------------------
__global__ void band_combine_t(const float* __restrict__ v,
                               const float* __restrict__ s,
                               const float* __restrict__ s_pre,
                               const float* __restrict__ gate,
                               u16* __restrict__ P) {
    __shared__ float bs[32][9];     // band weights for rows n0..n0+31
    __shared__ float tile[32][33];  // transpose staging (+1 pad)
    const int n0 = blockIdx.x * 32;
    const int d0 = blockIdx.y * 32;
    const int tx = threadIdx.x;     // 0..31
    const int ty = threadIdx.y;     // 0..7
    const int tid = ty * 32 + tx;

    const float sig = 1.0f / (1.0f + __expf(-gate[0]));
    // spdiags segment bases for off = -4..4 (lengths N-|off|)
    const int base[9] = {0, 4092, 8185, 12279, 16374, 20470, 24565, 28659, 32752};
    for (int t = tid; t < 288; t += 256) {
        int nl = t / 9, o = t - nl * 9;
        int n = n0 + nl, off = o - 4, col = n + off;
        float val = 0.0f;
        if (col >= 0 && col < N_DIM) {
            // off>=0: s[base+n]; off<0: s[base+n+off] = s[base+col]
            int idx = (off >= 0) ? (base[o] + n) : (base[o] + col);
            val = s[idx] * sig;
        }
        if (off == 0) val += s_pre[n];
        bs[nl][o] = val;
    }
    __syncthreads();

    #pragma unroll
    for (int i = 0; i < 4; ++i) {
        int nl = ty + 8 * i;
        int n = n0 + nl;
        int d = d0 + tx;
        float acc = 0.0f;
        #pragma unroll
        for (int o = 0; o < 9; ++o) {
            int src = n + o - 4;
            float vv = ((unsigned)src < (unsigned)N_DIM) ? v[(size_t)src * N_DIM + d] : 0.0f;
            acc += bs[nl][o] * vv;
        }
        tile[nl][tx] = acc;
    }
    __syncthreads();
    #pragma unroll
    for (int i = 0; i < 4; ++i) {
        int dl = ty + 8 * i;
        P[(size_t)(d0 + dl) * N_DIM + (n0 + tx)] = f2bf(tile[tx][dl]);
    }
}

// ---------------------------------------------------------------------------
// Dual fp32 -> bf16 cast (float4 vectorized), one launch for u and x.
// ---------------------------------------------------------------------------
__global__ void cvt2_bf16(const float* __restrict__ a, u16* __restrict__ oa, int na4,
                          const float* __restrict__ b, u16* __restrict__ ob, int nb4) {
    int i = blockIdx.x * blockDim.x + threadIdx.x;
    if (i < na4) {
        float4 f = ((const float4*)a)[i];
        ushort4 o;
        o.x = f2bf(f.x); o.y = f2bf(f.y); o.z = f2bf(f.z); o.w = f2bf(f.w);
        ((ushort4*)oa)[i] = o;
    } else {
        int j = i - na4;
        if (j < nb4) {
            float4 f = ((const float4*)b)[j];
            ushort4 o;
            o.x = f2bf(f.x); o.y = f2bf(f.y); o.z = f2bf(f.z); o.w = f2bf(f.w);
            ((ushort4*)ob)[j] = o;
        }
    }
}

// ---------------------------------------------------------------------------
// TN GEMM: C[m,n] = sum_k A[m,k]*B[n,k], A/B bf16 row-major.
// 128x128 tile, BK=32, 4 waves 2x2, 4x4 MFMA 16x16x32 per wave.
// XOR chunk swizzle kills ds_read_b128 bank conflicts:
//   LDS chunk (row r, slot c) holds global k-chunk c ^ ((r>>1)&3).
// 1D grid with 8-m-tile supertile bands for L2 locality.
// ---------------------------------------------------------------------------
template <bool OUT_BF16>
__global__ __launch_bounds__(256)
void gemm_tn(const u16* __restrict__ A, const u16* __restrict__ B,
             float* __restrict__ Cf, u16* __restrict__ Cb,
             int M, int N, int K) {
    __shared__ u16 As[128 * 32];
    __shared__ u16 Bs[128 * 32];
    const int tid  = threadIdx.x;
    const int lane = tid & 63;
    const int wave = tid >> 6;
    const int wm = wave >> 1;
    const int wn = wave & 1;

    // supertile swizzle: bands of 8 m-tiles, n fastest-within-band second
    const int tn   = N >> 7;                 // 32 for both GEMMs -> 8*tn = 256 (pow2)
    const int band = blockIdx.x >> 8;
    const int loc  = blockIdx.x & 255;
    const long m0 = (long)(band * 8 + (loc & 7)) << 7;
    const long n0 = (long)(loc >> 3) << 7;
    (void)tn;

    const u16* Ab = A + m0 * K;
    const u16* Bb = B + n0 * K;

    f32x4 acc[4][4];
    #pragma unroll
    for (int i = 0; i < 4; ++i)
        #pragma unroll
        for (int j = 0; j < 4; ++j)
            acc[i][j] = (f32x4){0.f, 0.f, 0.f, 0.f};

    // staging: thread tid stages 16B chunk (row = tid>>2, swizzled k-chunk)
    const int row = tid >> 2;
    const int kcs = (((tid & 3) ^ ((tid >> 3) & 3))) * 8;  // swizzled source offset (elems)

    const u16* pA0 = Ab + (long)row * K + kcs;
    const u16* pA1 = pA0 + 64L * K;
    const u16* pB0 = Bb + (long)row * K + kcs;
    const u16* pB1 = pB0 + 64L * K;

    // fragment reads: lane (ml, q) wants row R, k-quad q -> swizzled slot q^((ml>>1)&3)
    const int ml  = lane & 15;
    const int kqe = ((lane >> 4) ^ ((ml >> 1) & 3)) * 8;
    const int aBase = ml * 32 + kqe;

    for (int kt = 0; kt < K; kt += 32) {
        __syncthreads();
        gl_lds16(pA0, &As[tid * 8]);
        gl_lds16(pA1, &As[2048 + tid * 8]);
        gl_lds16(pB0, &Bs[tid * 8]);
        gl_lds16(pB1, &Bs[2048 + tid * 8]);
        pA0 += 32; pA1 += 32; pB0 += 32; pB1 += 32;
        __syncthreads();

        bf16x8 af[4], bfr[4];
        #pragma unroll
        for (int i = 0; i < 4; ++i)
            af[i] = *(const bf16x8*)&As[(wm * 64 + i * 16) * 32 + aBase];
        #pragma unroll
        for (int i = 0; i < 4; ++i)
            bfr[i] = *(const bf16x8*)&Bs[(wn * 64 + i * 16) * 32 + aBase];

        #pragma unroll
        for (int mi = 0; mi < 4; ++mi)
            #pragma unroll
            for (int ni = 0; ni < 4; ++ni)
                acc[mi][ni] = __builtin_amdgcn_mfma_f32_16x16x32_bf16(
                    af[mi], bfr[ni], acc[mi][ni], 0, 0, 0);
    }

    // Epilogue. D layout: col = lane&15, row = (lane>>4)*4 + reg  [m89]
    const int cn = lane & 15;
    const int rg = lane >> 4;
    #pragma unroll
    for (int mi = 0; mi < 4; ++mi) {
        #pragma unroll
        for (int ni = 0; ni < 4; ++ni) {
            const long mb = m0 + wm * 64 + mi * 16 + rg * 4;
            const long nn = n0 + wn * 64 + ni * 16 + cn;
            #pragma unroll
            for (int r = 0; r < 4; ++r) {
                const long off = (mb + r) * N + nn;
                if (OUT_BF16) Cb[off] = f2bf(acc[mi][ni][r]);
                else          Cf[off] = acc[mi][ni][r];
            }
        }
    }
}

// ---------------------------------------------------------------------------
// out = x @ ((M v)^T u^T):
//   P   = (M v)^T bf16 [D_IN, N]     (fused band build + combine + transpose)
//   Ubf = bf16(u), Xbf = bf16(x)     (one dual-cast launch)
//   Wt  = u M v = GEMM_TN(Ubf, P)    [D_OUT, D_IN] bf16
//   out = GEMM_TN(Xbf, Wt)           [B*S, D_OUT] fp32
// ---------------------------------------------------------------------------
extern "C" void kernel_launch(void* const* d_in, const int* in_sizes, int n_in,
                              void* d_out, int out_size, void* d_ws, size_t ws_size,
                              hipStream_t stream) {
    const float* x     = (const float*)d_in[0];   // [4, 2048, 4096]
    const float* u     = (const float*)d_in[1];   // [4096, 4096]
    const float* v     = (const float*)d_in[2];   // [4096, 4096]
    const float* s_pre = (const float*)d_in[3];   // [4096]
    const float* s     = (const float*)d_in[4];   // [36844]
    const float* gate  = (const float*)d_in[5];   // [1]
    // d_in[6]=row, d_in[7]=col: spdiags layout reconstructed analytically.
    float* out = (float*)d_out;                    // [8192, 4096]

    const int BS = 8192;
    const size_t NN = (size_t)N_DIM * N_DIM;

    char* ws = (char*)d_ws;
    u16* P   = (u16*)ws;                 // 32 MB
    u16* Ubf = (u16*)(ws + NN * 2);      // 32 MB
    u16* Wt  = (u16*)(ws + NN * 4);      // 32 MB
    u16* Xbf = (u16*)(ws + NN * 6);      // 64 MB

    // 1. P = (M v)^T in bf16 (band weights built in-kernel)
    band_combine_t<<<dim3(128, 128), dim3(32, 8), 0, stream>>>(v, s, s_pre, gate, P);

    // 2. bf16 casts (u then x, one launch)
    const int na4 = (int)(NN / 4);                       // u
    const int nb4 = (int)((size_t)BS * N_DIM / 4);       // x
    cvt2_bf16<<<(na4 + nb4 + 255) / 256, 256, 0, stream>>>(u, Ubf, na4, x, Xbf, nb4);

    // 3. Wt = Ubf @ P^T  [4096 x 4096] bf16
    gemm_tn<true><<<(N_DIM / 128) * (N_DIM / 128), 256, 0, stream>>>(
        Ubf, P, nullptr, Wt, N_DIM, N_DIM, N_DIM);

    // 4. out = Xbf @ Wt^T  [8192 x 4096] fp32
    gemm_tn<false><<<(BS / 128) * (N_DIM / 128), 256, 0, stream>>>(
        Xbf, Wt, out, nullptr, BS, N_DIM, N_DIM);
}